// Round 14
// baseline (126.667 us; speedup 1.0000x reference)
//
#include <hip/hip_runtime.h>
#include <hip/hip_bf16.h>
#include <math.h>

#define BB 2
#define LL 2048
#define DD 256
#define NT (BB*LL)      // 4096 tokens
#define HCOLS 896       // ke(256) qe(256) lke(256) gate(128)
#define NCOLS 1152      // HCOLS + v(256)
#define KBIG 768        // split-bf16 concat K: [hi|lo-cross|hi-cross]
#define FDIM 80         // 32 bank + 8 joint + 32 pos + 8 pad
#define CC 64           // chunk length
#define NC (NT/CC)      // 64 chunks
#define NCB (LL/CC)     // 32 chunks per batch
#define SST (FDIM*DD)   // 20480 floats per chunk state
#define PI_F 3.14159265358979323846f

typedef __attribute__((ext_vector_type(8))) short s8frag;
typedef __attribute__((ext_vector_type(4))) float f4acc;

// global_load_lds 16B: LDS dest = uniform base + lane*16 (linear); global src per-lane.
#define GLDS16(g, l) __builtin_amdgcn_global_load_lds( \
    (const __attribute__((address_space(1))) void*)(g), \
    (__attribute__((address_space(3))) void*)(l), 16, 0, 0)

__device__ __forceinline__ float gelu_erf(float v) {
    return 0.5f * v * (1.0f + erff(v * 0.70710678118654752440f));
}
__device__ __forceinline__ float sigmoidf_(float v) {
    return 1.0f / (1.0f + expf(-v));
}

// ---------------- K0: fused prep (x hi/lo | BT+OWT transpose tiles | W2T | bias)
#define K0A_BLKS (NT * DD / 4 / 256)          // 1024
#define K0B_TW   22                           // 18 BT tiles + 4 OWT tiles per k-row
#define K0B_BLKS ((KBIG / 64) * K0B_TW)       // 12*22 = 264
#define K0C_BLKS (4 * 16 * 768 / 256)         // 192
#define K0D_BLKS 5                            // bias (1152 cols)
__global__ __launch_bounds__(256) void k0_prep(
    const float* __restrict__ x,
    const float* __restrict__ ke_w1, const float* __restrict__ ke_b1,
    const float* __restrict__ qe_w1, const float* __restrict__ qe_b1,
    const float* __restrict__ lke_w1, const float* __restrict__ lke_b1,
    const float* __restrict__ gate_w1, const float* __restrict__ gate_b1,
    const float* __restrict__ v_w, const float* __restrict__ v_b,
    const float* __restrict__ ke_w2, const float* __restrict__ qe_w2,
    const float* __restrict__ lke_w2, const float* __restrict__ gate_w2,
    const float* __restrict__ out_w,
    __hip_bfloat16* __restrict__ xhi, __hip_bfloat16* __restrict__ xlo,
    __hip_bfloat16* __restrict__ BT, float* __restrict__ bcat,
    __hip_bfloat16* __restrict__ W2T, __hip_bfloat16* __restrict__ OWT)
{
    __shared__ float tile[64][65];
    const int b = blockIdx.x, tid = threadIdx.x;
    if (b < K0A_BLKS) {
        int idx = b * 256 + tid;
        float4 v = reinterpret_cast<const float4*>(x)[idx];
        float vv[4] = {v.x, v.y, v.z, v.w};
        #pragma unroll
        for (int j = 0; j < 4; ++j) {
            __hip_bfloat16 h = __float2bfloat16(vv[j]);
            xhi[idx * 4 + j] = h;
            xlo[idx * 4 + j] = __float2bfloat16(vv[j] - __bfloat162float(h));
        }
    } else if (b < K0A_BLKS + K0B_BLKS) {
        int bb = b - K0A_BLKS;
        int bk = bb / K0B_TW, bn = bb - bk * K0B_TW;
        int kp0 = bk * 64, n0 = bn * 64;
        int seg = kp0 >> 8;
        int k0 = kp0 - seg * 256;
        #pragma unroll 4
        for (int i = 0; i < 16; ++i) {
            int kl = i * 4 + (tid >> 6);
            int nl = tid & 63;
            int k = k0 + kl, n = n0 + nl;
            float w;
            if (n < 256)       w = ke_w1[k * 256 + n];
            else if (n < 512)  w = qe_w1[k * 256 + (n - 256)];
            else if (n < 768)  w = lke_w1[k * 256 + (n - 512)];
            else if (n < 896)  w = gate_w1[k * 128 + (n - 768)];
            else if (n < 1152) w = v_w[k * 256 + (n - 896)];
            else               w = out_w[k * 256 + (n - 1152)];
            tile[kl][nl] = w;
        }
        __syncthreads();
        #pragma unroll 4
        for (int i = 0; i < 16; ++i) {
            int nl = i * 4 + (tid >> 6);
            int kpl = tid & 63;
            float w = tile[kpl][nl];
            __hip_bfloat16 hi = __float2bfloat16(w);
            __hip_bfloat16 out = (seg == 1)
                ? __float2bfloat16(w - __bfloat162float(hi)) : hi;
            if (n0 < 1152)
                BT[(size_t)(n0 + nl) * KBIG + kp0 + kpl] = out;
            else
                OWT[(size_t)(n0 + nl - 1152) * KBIG + kp0 + kpl] = out;
        }
    } else if (b < K0A_BLKS + K0B_BLKS + K0C_BLKS) {
        int idx = (b - K0A_BLKS - K0B_BLKS) * 256 + tid;  // over 4*16*768
        int g = idx / (16 * 768);
        int rem = idx - g * (16 * 768);
        int n = rem / 768;
        int kp = rem - n * 768;
        float w = 0.0f;
        int seg;
        if (g < 3) {
            seg = kp >> 8;
            int k = kp & 255;
            const float* W = (g == 0) ? ke_w2 : (g == 1) ? qe_w2 : lke_w2;
            w = W[k * 16 + n];
        } else {
            seg = kp >> 7;
            int k = kp & 127;
            if (n == 0 && kp < 384) w = gate_w2[k];
            else { seg = 0; w = 0.0f; }
        }
        __hip_bfloat16 hi = __float2bfloat16(w);
        __hip_bfloat16 out = (seg == 1) ? __float2bfloat16(w - __bfloat162float(hi)) : hi;
        W2T[idx] = out;
    } else {
        int n = (b - K0A_BLKS - K0B_BLKS - K0C_BLKS) * 256 + tid;
        if (n < NCOLS) {
            float bia;
            if (n < 256)      bia = ke_b1[n];
            else if (n < 512) bia = qe_b1[n - 256];
            else if (n < 768) bia = lke_b1[n - 512];
            else if (n < 896) bia = gate_b1[n - 768];
            else              bia = v_b[n - 896];
            bcat[n] = bia;
        }
    }
}

// ---------------- K1: MFMA GEMM  C[4096][1152] = A[4096][768] @ B[768][1152]
// 128x128 tile, BK=64, single-buffer (32KB LDS). 16 ds_read : 32 MFMA per k-step
// (m97-class 0.5 ratio). grid (32, 9).
__global__ __launch_bounds__(256) void k1_mfma(
    const __hip_bfloat16* __restrict__ xhi, const __hip_bfloat16* __restrict__ xlo,
    const __hip_bfloat16* __restrict__ BT, const float* __restrict__ bcat,
    __hip_bfloat16* __restrict__ Hhi, __hip_bfloat16* __restrict__ Hlo,
    float* __restrict__ V)
{
    __shared__ __align__(16) short As[128 * 64];
    __shared__ __align__(16) short Bs[128 * 64];
    const int tid = threadIdx.x;
    const int wave = tid >> 6, lane = tid & 63;
    const int wr = wave >> 1, wc = wave & 1;
    const int bm = blockIdx.x, bn = blockIdx.y;
    const int lg = lane >> 4, lr = lane & 15;

    f4acc acc[4][4] = {};

    for (int kt = 0; kt < KBIG / 64; ++kt) {
        const int k0 = kt * 64;
        const __hip_bfloat16* xsrc = (kt < 8) ? xhi : xlo;
        const int kcol = (kt < 8) ? (k0 & 255) : (k0 - 512);
        #pragma unroll
        for (int j = 0; j < 4; ++j) {        // A rows wave*32 .. +32
            int r0 = wave * 32 + j * 8;
            int row = r0 + (lane >> 3);
            int ch = (lane & 7) ^ (row & 7);
            GLDS16(xsrc + (size_t)(bm * 128 + row) * DD + kcol + ch * 8, &As[r0 * 64]);
        }
        #pragma unroll
        for (int j = 0; j < 4; ++j) {        // B rows wave*32 .. +32
            int r0 = wave * 32 + j * 8;
            int row = r0 + (lane >> 3);
            int ch = (lane & 7) ^ (row & 7);
            GLDS16(BT + (size_t)(bn * 128 + row) * KBIG + k0 + ch * 8, &Bs[r0 * 64]);
        }
        __syncthreads();
        #pragma unroll
        for (int kk = 0; kk < 2; ++kk) {
            s8frag a[4], b[4];
            #pragma unroll
            for (int i = 0; i < 4; ++i) {
                int arow = wr * 64 + i * 16 + lr;
                int slot = (kk * 4 + lg) ^ (arow & 7);
                a[i] = *reinterpret_cast<const s8frag*>(&As[arow * 64 + slot * 8]);
                int brow = wc * 64 + i * 16 + lr;
                int bslot = (kk * 4 + lg) ^ (brow & 7);
                b[i] = *reinterpret_cast<const s8frag*>(&Bs[brow * 64 + bslot * 8]);
            }
            #pragma unroll
            for (int mi = 0; mi < 4; ++mi)
                #pragma unroll
                for (int ni = 0; ni < 4; ++ni)
                    acc[mi][ni] = __builtin_amdgcn_mfma_f32_16x16x32_bf16(
                        a[mi], b[ni], acc[mi][ni], 0, 0, 0);
        }
        __syncthreads();
    }

    #pragma unroll
    for (int ni = 0; ni < 4; ++ni) {
        int n = bn * 128 + wc * 64 + ni * 16 + lr;
        float bia = bcat[n];
        #pragma unroll
        for (int mi = 0; mi < 4; ++mi) {
            #pragma unroll
            for (int r = 0; r < 4; ++r) {
                int m = bm * 128 + wr * 64 + mi * 16 + lg * 4 + r;
                float v = acc[mi][ni][r] + bia;
                if (n < HCOLS) {
                    float hv = gelu_erf(v);
                    __hip_bfloat16 h = __float2bfloat16(hv);
                    Hhi[(size_t)m * HCOLS + n] = h;
                    Hlo[(size_t)m * HCOLS + n] = __float2bfloat16(hv - __bfloat162float(h));
                } else {
                    V[(size_t)m * DD + (n - HCOLS)] = v;
                }
            }
        }
    }
}

// ---------------- K2: fused second-layer MFMA + phases + features (16 tokens/block)
__global__ __launch_bounds__(256) void k2_fused(
    const __hip_bfloat16* __restrict__ Hhi, const __hip_bfloat16* __restrict__ Hlo,
    const __hip_bfloat16* __restrict__ W2T,
    const float* __restrict__ ke_b2, const float* __restrict__ qe_b2,
    const float* __restrict__ lke_b2, const float* __restrict__ gate_b2,
    const float* __restrict__ set_weights, const float* __restrict__ pos_weight,
    const float* __restrict__ ltm_weight, const float* __restrict__ ltm_count,
    const float* __restrict__ pos_freqs,
    float* __restrict__ Fk, float* __restrict__ Fq, float* __restrict__ Fql,
    float* __restrict__ J)
{
    __shared__ float c2s[16][52];   // activated phases: cols 0..48 used
    const int tid = threadIdx.x;
    const int g = tid >> 6, lane = tid & 63;
    const int lg = lane >> 4, lr = lane & 15;
    const int t0 = blockIdx.x * 16;

    {
        const int seglen = (g < 3) ? 256 : 128;
        const int gbase = (g < 3) ? g * 256 : 768;
        const int nsteps = (g < 3) ? 24 : 12;
        const __hip_bfloat16* wbase = W2T + (size_t)(g * 16 + lr) * 768;
        f4acc acc = {};
        for (int kt = 0; kt < nsteps; ++kt) {
            const int kp = kt * 32;
            const int seg = kp / seglen;
            const int kk = kp - seg * seglen;
            const __hip_bfloat16* asrc = (seg < 2) ? Hhi : Hlo;
            s8frag b = *reinterpret_cast<const s8frag*>(wbase + kp + lg * 8);
            s8frag a = *reinterpret_cast<const s8frag*>(
                asrc + (size_t)(t0 + lr) * HCOLS + gbase + kk + lg * 8);
            acc = __builtin_amdgcn_mfma_f32_16x16x32_bf16(a, b, acc, 0, 0, 0);
        }
        int col = g * 16 + lr;
        if (col < 49) {
            #pragma unroll
            for (int r = 0; r < 4; ++r)
                c2s[lg * 4 + r][col] = acc[r];
        }
    }
    __syncthreads();

    for (int i = tid; i < 16 * 64; i += 256) {
        int t = i >> 6, c = i & 63;
        if (c < 49) {
            float a = c2s[t][c];
            float val;
            if (c < 16)      val = tanhf(a + ke_b2[c]) * PI_F;
            else if (c < 32) val = tanhf(a + qe_b2[c - 16]) * PI_F;
            else if (c < 48) val = tanhf(a + lke_b2[c - 32]) * PI_F;
            else             val = sigmoidf_(a + gate_b2[0]);
            c2s[t][c] = val;
        }
    }
    __syncthreads();

    float sw[4];
    {
        float s0 = set_weights[0], s1 = set_weights[1], s2 = set_weights[2], s3 = set_weights[3];
        float mx = fmaxf(fmaxf(s0, s1), fmaxf(s2, s3));
        float e0 = expf(s0 - mx), e1 = expf(s1 - mx), e2 = expf(s2 - mx), e3 = expf(s3 - mx);
        float inv = 1.0f / (e0 + e1 + e2 + e3);
        sw[0] = e0 * inv; sw[1] = e1 * inv; sw[2] = e2 * inv; sw[3] = e3 * inv;
    }
    const float spw = sigmoidf_(pos_weight[0]);
    const float altm = sigmoidf_(ltm_weight[0]) / sqrtf(fmaxf(ltm_count[0], 1.0f) * 16.0f);
    const int sg = tid >> 5, sl = tid & 31;

    for (int tr = 0; tr < 2; ++tr) {
        const int lt = tr * 8 + sg;
        const int t = t0 + lt;
        const float gg = c2s[lt][48];
        const float aq = gg * 0.2f;
        const float apos = (1.0f - gg) * spw;
        const int l = t & (LL - 1);
        float* fkr  = Fk  + (size_t)t * FDIM;
        float* fqr  = Fq  + (size_t)t * FDIM;
        float* fqlr = Fql + (size_t)t * 32;

        if (sl < 16) {
            int p = sl;
            float sk, ck; sincosf(c2s[lt][p], &sk, &ck);
            fkr[2 * p] = ck; fkr[2 * p + 1] = sk;
            float sq, cq; sincosf(c2s[lt][16 + p], &sq, &cq);
            float wq = aq * sw[p >> 2];
            fqr[2 * p] = wq * cq; fqr[2 * p + 1] = wq * sq;
            float sl_, cl_; sincosf(c2s[lt][32 + p], &sl_, &cl_);
            fqlr[2 * p] = altm * cl_; fqlr[2 * p + 1] = altm * sl_;
            float th = (float)l * pos_freqs[p] * (2.0f * PI_F);
            float sp, cp; sincosf(th, &sp, &cp);
            fkr[40 + 2 * p] = cp; fkr[41 + 2 * p] = sp;
            fqr[40 + 2 * p] = apos * cp; fqr[41 + 2 * p] = apos * sp;
        } else if (sl < 20) {
            int p = sl - 16;
            float pjk = c2s[lt][p] + c2s[lt][p + 4] + c2s[lt][p + 8] + c2s[lt][p + 12];
            float pjq = c2s[lt][16 + p] + c2s[lt][20 + p] + c2s[lt][24 + p] + c2s[lt][28 + p];
            float sjk, cjk; sincosf(pjk, &sjk, &cjk);
            float sjq, cjq; sincosf(pjq, &sjq, &cjq);
            fkr[32 + 2 * p] = cjk; fkr[33 + 2 * p] = sjk;
            fqr[32 + 2 * p] = aq * cjq; fqr[33 + 2 * p] = aq * sjq;
            J[(size_t)(2 * p) * NT + t] = cjk;
            J[(size_t)(2 * p + 1) * NT + t] = sjk;
        } else if (sl < 24) {
            int p = sl - 20;
            fkr[72 + 2 * p] = 0.0f; fkr[73 + 2 * p] = 0.0f;
            fqr[72 + 2 * p] = 0.0f; fqr[73 + 2 * p] = 0.0f;
        }
    }
}

// ---------------- K3a: exclusive scan of joint-key phasors (from compact J) -> wg[token]
__device__ __forceinline__ int swz2048(int l) {
    return (l & ~31) | ((l ^ (l >> 5)) & 31);
}
__global__ __launch_bounds__(512) void k3a_scan(
    const float* __restrict__ J, float* __restrict__ wg,
    const float* __restrict__ resonance_scale, const float* __restrict__ resonance_threshold,
    const float* __restrict__ surprise_scale, const float* __restrict__ surprise_bias)
{
    __shared__ float km[8 * LL];
    const int b = blockIdx.x;
    const int tid = threadIdx.x;
    const int w = tid >> 6;     // series 0..7
    const int lane = tid & 63;
    {
        float v[32];
        float s = 0.0f;
        int l0 = lane * 32;
        const float4* src = reinterpret_cast<const float4*>(
            J + (size_t)w * NT + b * LL + l0);
        #pragma unroll
        for (int i = 0; i < 8; ++i) {
            float4 q = src[i];
            v[4 * i + 0] = q.x; v[4 * i + 1] = q.y;
            v[4 * i + 2] = q.z; v[4 * i + 3] = q.w;
            s += q.x + q.y + q.z + q.w;
        }
        float local = s;
        #pragma unroll
        for (int off = 1; off < 64; off <<= 1) {
            float n = __shfl_up(s, off);
            if (lane >= off) s += n;
        }
        float run = s - local;   // exclusive base
        #pragma unroll 4
        for (int i = 0; i < 32; ++i) { km[w * LL + swz2048(l0 + i)] = run; run += v[i]; }
    }
    __syncthreads();
    const float sc  = fminf(fmaxf(resonance_scale[0], 1.0f), 20.0f);
    const float th  = fminf(fmaxf(resonance_threshold[0], 0.1f), 0.9f);
    const float ssc = surprise_scale[0];
    const float sbi = surprise_bias[0];
    for (int q = 0; q < 4; ++q) {
        int l = tid + 512 * q;
        int ls = swz2048(l);
        float rm = 0.0f;
        #pragma unroll
        for (int p = 0; p < 4; ++p) {
            float re = km[(2 * p) * LL + ls], im = km[(2 * p + 1) * LL + ls];
            rm += sqrtf(re * re + im * im);
        }
        rm *= 0.25f;
        float nr = rm / sqrtf(fmaxf((float)l, 1.0f));
        float sur = 0.5f * (1.0f - tanhf(sc * (nr - th)));
        wg[b * LL + l] = sigmoidf_(ssc * (sur - 0.5f) + sbi);
    }
}

// ---------------- K4a: per-chunk key state S_c = (gated F_k_c)^T @ V_c   (80 x 256)
__global__ __launch_bounds__(256) void k4a_state(
    const float* __restrict__ Fk, const float* __restrict__ wg,
    const float* __restrict__ V, float* __restrict__ S)
{
    __shared__ __align__(16) float fk[CC][FDIM];
    const int c = blockIdx.x;
    const int f0 = blockIdx.y * 20;       // f quarter
    const int tid = threadIdx.x;          // = output dim d
    for (int i = tid; i < CC * FDIM; i += 256) {
        int r = i / FDIM, cx = i - r * FDIM;
        float f = Fk[(size_t)c * CC * FDIM + i];
        if (cx < 40) f *= wg[c * CC + r];   // fused write-gate (dims 0..39)
        fk[r][cx] = f;
    }
    __syncthreads();
    float acc[20];
    #pragma unroll
    for (int f = 0; f < 20; ++f) acc[f] = 0.0f;
    const float* vp = V + (size_t)c * CC * DD + tid;
    #pragma unroll 8
    for (int r = 0; r < CC; ++r) {
        float v = vp[(size_t)r * DD];
        #pragma unroll
        for (int g = 0; g < 5; ++g) {
            float4 q = *reinterpret_cast<const float4*>(&fk[r][f0 + 4 * g]);
            acc[4 * g + 0] += q.x * v; acc[4 * g + 1] += q.y * v;
            acc[4 * g + 2] += q.z * v; acc[4 * g + 3] += q.w * v;
        }
    }
    float* sp = S + (size_t)c * SST + tid;
    #pragma unroll
    for (int f = 0; f < 20; ++f) sp[(size_t)(f0 + f) * DD] = acc[f];
}

// ---------------- K4b: exclusive prefix-sum of chunk states (full-register ILP)
__global__ __launch_bounds__(256) void k4b_scan(
    const float* __restrict__ S, float* __restrict__ M)
{
    const int e = blockIdx.x * 256 + threadIdx.x;   // element in [0, SST)
    const int b = blockIdx.y;
    const float* sp = S + (size_t)(b * NCB) * SST + e;
    float* mp = M + (size_t)(b * NCB) * SST + e;
    float v[NCB];
    #pragma unroll
    for (int cc = 0; cc < NCB; ++cc) v[cc] = sp[(size_t)cc * SST];  // 32 indep loads
    float run = 0.0f;
    #pragma unroll
    for (int cc = 0; cc < NCB; ++cc) { float t = v[cc]; v[cc] = run; run += t; }
    #pragma unroll
    for (int cc = 0; cc < NCB; ++cc) mp[(size_t)cc * SST] = v[cc];
}

// ---------------- K4c: retrieval + LTM + fused LayerNorm -> bf16 hi/lo split
// grid (NC, 8): 8-row slices, 512 blocks (2/CU). Emits Hnhi/Hnlo.
__global__ __launch_bounds__(256) void k4c_ln(
    const float* __restrict__ Fq, const float* __restrict__ Fk,
    const float* __restrict__ wg, const float* __restrict__ Fql,
    const float* __restrict__ V, const float* __restrict__ M,
    const float* __restrict__ ltm_mem,
    const float* __restrict__ gln, const float* __restrict__ bln,
    __hip_bfloat16* __restrict__ Hnhi, __hip_bfloat16* __restrict__ Hnlo)
{
    __shared__ __align__(16) float fq[8][FDIM];
    __shared__ __align__(16) float fkS[CC * 96];   // swizzled: [r][cx ^ ((r&7)<<2)]
    __shared__ __align__(16) float sc[8][68];
    const int c = blockIdx.x;
    const int h = blockIdx.y;
    const int r0 = h * 8;
    const int nrows = r0 + 8;           // causal extent of needed k rows
    const int tid = threadIdx.x;
    const int wave = tid >> 6, lane = tid & 63;

    for (int i = tid; i < 8 * FDIM; i += 256) {
        int r = i / FDIM, cx = i - r * FDIM;
        fq[r][cx] = Fq[(size_t)(c * CC + r0 + r) * FDIM + cx];
    }
    for (int i = tid; i < nrows * FDIM; i += 256) {
        int r = i / FDIM, cx = i - r * FDIM;
        float f = Fk[(size_t)c * CC * FDIM + i];
        if (cx < 40) f *= wg[c * CC + r];   // fused write-gate
        fkS[r * 96 + (cx ^ ((r & 7) << 2))] = f;
    }
    __syncthreads();

    #pragma unroll
    for (int q = 0; q < 2; ++q) {
        int idx = tid + 256 * q;
        int i = idx >> 6, j = idx & 63;
        float s = 0.0f;
        if (r0 + i >= j) {
            const int sw = (j & 7) << 2;
            #pragma unroll
            for (int g = 0; g < 20; ++g) {
                float4 a = *reinterpret_cast<const float4*>(&fq[i][4 * g]);
                float4 b = *reinterpret_cast<const float4*>(&fkS[j * 96 + ((4 * g) ^ sw)]);
                s += a.x * b.x + a.y * b.y + a.z * b.z + a.w * b.w;
            }
        }
        sc[i][j] = s;
    }
    __syncthreads();

    const int d = tid;
    float acc[8];
    #pragma unroll
    for (int i = 0; i < 8; ++i) acc[i] = 0.0f;

    const float* mp = M + (size_t)c * SST + d;
    #pragma unroll 2
    for (int g = 0; g < 20; ++g) {
        float m0 = mp[(size_t)(4 * g + 0) * DD];
        float m1 = mp[(size_t)(4 * g + 1) * DD];
        float m2 = mp[(size_t)(4 * g + 2) * DD];
        float m3 = mp[(size_t)(4 * g + 3) * DD];
        #pragma unroll
        for (int i = 0; i < 8; ++i) {
            float4 a = *reinterpret_cast<const float4*>(&fq[i][4 * g]);
            acc[i] += a.x * m0 + a.y * m1 + a.z * m2 + a.w * m3;
        }
    }
    const float* vp = V + (size_t)c * CC * DD + d;
    const int j4max = nrows >> 2;
    #pragma unroll 2
    for (int j4 = 0; j4 < j4max; ++j4) {
        float v0 = vp[(size_t)(4 * j4 + 0) * DD];
        float v1 = vp[(size_t)(4 * j4 + 1) * DD];
        float v2 = vp[(size_t)(4 * j4 + 2) * DD];
        float v3 = vp[(size_t)(4 * j4 + 3) * DD];
        #pragma unroll
        for (int i = 0; i < 8; ++i) {
            float4 s4 = *reinterpret_cast<const float4*>(&sc[i][4 * j4]);
            acc[i] += s4.x * v0 + s4.y * v1 + s4.z * v2 + s4.w * v3;
        }
    }
    // LTM epilogue
    float mre[16], mim[16];
    #pragma unroll
    for (int p = 0; p < 16; ++p) {
        mre[p] = ltm_mem[((size_t)p * DD + d) * 2];
        mim[p] = ltm_mem[((size_t)p * DD + d) * 2 + 1];
    }
    __syncthreads();
    {
        int r = tid >> 5, p = tid & 31;
        sc[r][p] = Fql[(size_t)(c * CC + r0 + r) * 32 + p];
    }
    __syncthreads();
    #pragma unroll
    for (int i = 0; i < 8; ++i) {
        float a = acc[i];
        #pragma unroll
        for (int p = 0; p < 16; ++p)
            a += sc[i][2 * p] * mre[p] + sc[i][2 * p + 1] * mim[p];
        acc[i] = a;
    }
    __syncthreads();

    // fused LayerNorm per row: wave shfl reduce + cross-wave via sc
    #pragma unroll
    for (int i = 0; i < 8; ++i) {
        float s = acc[i], s2 = acc[i] * acc[i];
        #pragma unroll
        for (int off = 1; off < 64; off <<= 1) {
            s  += __shfl_xor(s, off);
            s2 += __shfl_xor(s2, off);
        }
        if (lane == 0) { sc[i][wave] = s; sc[i][4 + wave] = s2; }
    }
    __syncthreads();
    const float gv = gln[d], bv = bln[d];
    __hip_bfloat16* hp = Hnhi + (size_t)(c * CC + r0) * DD + d;
    __hip_bfloat16* lp = Hnlo + (size_t)(c * CC + r0) * DD + d;
    #pragma unroll 1
    for (int i = 0; i < 8; ++i) {
        float s  = sc[i][0] + sc[i][1] + sc[i][2] + sc[i][3];
        float s2 = sc[i][4] + sc[i][5] + sc[i][6] + sc[i][7];
        float mu = s * (1.0f / 256.0f);
        float var = s2 * (1.0f / 256.0f) - mu * mu;
        float rstd = rsqrtf(var + 1e-5f);
        float hn = (acc[i] - mu) * rstd * gv + bv;
        __hip_bfloat16 hb = __float2bfloat16(hn);
        hp[(size_t)i * DD] = hb;
        lp[(size_t)i * DD] = __float2bfloat16(hn - __bfloat162float(hb));
    }
}

// ---------------- K5b: MFMA GEMM  out[4096][256] = [Hnhi|Hnhi|Hnlo] @ OWT^T + out_b
__global__ __launch_bounds__(256) void k5b_mfma(
    const __hip_bfloat16* __restrict__ Hnhi, const __hip_bfloat16* __restrict__ Hnlo,
    const __hip_bfloat16* __restrict__ OWT, const float* __restrict__ out_b,
    float* __restrict__ out)
{
    __shared__ __align__(16) short As[64 * 64];
    __shared__ __align__(16) short Bs[64 * 64];
    const int tid = threadIdx.x;
    const int wave = tid >> 6, lane = tid & 63;
    const int wr = wave >> 1, wc = wave & 1;
    const int bm = blockIdx.x, bn = blockIdx.y;
    const int lg = lane >> 4, lr = lane & 15;

    f4acc acc[2][2] = {};

    for (int kt = 0; kt < KBIG / 64; ++kt) {
        const int k0 = kt * 64;
        const __hip_bfloat16* asrc = (kt < 8) ? Hnhi : Hnlo;
        const int kcol = (kt < 8) ? (k0 & 255) : (k0 - 512);
        #pragma unroll
        for (int j = 0; j < 2; ++j) {
            int r0 = wave * 16 + j * 8;
            int row = r0 + (lane >> 3);
            int ch = (lane & 7) ^ (row & 7);
            GLDS16(asrc + (size_t)(bm * 64 + row) * DD + kcol + ch * 8, &As[r0 * 64]);
            GLDS16(OWT + (size_t)(bn * 64 + row) * KBIG + k0 + ch * 8, &Bs[r0 * 64]);
        }
        __syncthreads();
        #pragma unroll
        for (int kk = 0; kk < 2; ++kk) {
            s8frag a[2], b[2];
            #pragma unroll
            for (int i = 0; i < 2; ++i) {
                int arow = wr * 32 + i * 16 + lr;
                int aslot = (kk * 4 + lg) ^ (arow & 7);
                a[i] = *reinterpret_cast<const s8frag*>(&As[arow * 64 + aslot * 8]);
                int brow = wc * 32 + i * 16 + lr;
                int bslot = (kk * 4 + lg) ^ (brow & 7);
                b[i] = *reinterpret_cast<const s8frag*>(&Bs[brow * 64 + bslot * 8]);
            }
            #pragma unroll
            for (int mi = 0; mi < 2; ++mi)
                #pragma unroll
                for (int ni = 0; ni < 2; ++ni)
                    acc[mi][ni] = __builtin_amdgcn_mfma_f32_16x16x32_bf16(
                        a[mi], b[ni], acc[mi][ni], 0, 0, 0);
        }
        __syncthreads();
    }

    #pragma unroll
    for (int ni = 0; ni < 2; ++ni) {
        int n = bn * 64 + wc * 32 + ni * 16 + lr;
        float ob = out_b[n];
        #pragma unroll
        for (int mi = 0; mi < 2; ++mi) {
            #pragma unroll
            for (int r = 0; r < 4; ++r) {
                int m = bm * 64 + wr * 32 + mi * 16 + lg * 4 + r;
                out[(size_t)m * DD + n] = acc[mi][ni][r] + ob;
            }
        }
    }
}

extern "C" void kernel_launch(void* const* d_in, const int* in_sizes, int n_in,
                              void* d_out, int out_size, void* d_ws, size_t ws_size,
                              hipStream_t stream)
{
    (void)in_sizes; (void)n_in; (void)out_size; (void)ws_size;
    const float* x        = (const float*)d_in[0];
    const float* ke_w1    = (const float*)d_in[1];
    const float* ke_b1    = (const float*)d_in[2];
    const float* ke_w2    = (const float*)d_in[3];
    const float* ke_b2    = (const float*)d_in[4];
    const float* qe_w1    = (const float*)d_in[5];
    const float* qe_b1    = (const float*)d_in[6];
    const float* qe_w2    = (const float*)d_in[7];
    const float* qe_b2    = (const float*)d_in[8];
    const float* v_w      = (const float*)d_in[9];
    const float* v_b      = (const float*)d_in[10];
    const float* out_ln_g = (const float*)d_in[11];
    const float* out_ln_b = (const float*)d_in[12];
    const float* out_w    = (const float*)d_in[13];
    const float* out_b    = (const float*)d_in[14];
    const float* set_weights = (const float*)d_in[15];
    const float* pos_weight  = (const float*)d_in[16];
    const float* gate_w1  = (const float*)d_in[17];
    const float* gate_b1  = (const float*)d_in[18];
    const float* gate_w2  = (const float*)d_in[19];
    const float* gate_b2  = (const float*)d_in[20];
    const float* lke_w1   = (const float*)d_in[21];
    const float* lke_b1   = (const float*)d_in[22];
    const float* lke_w2   = (const float*)d_in[23];
    const float* lke_b2   = (const float*)d_in[24];
    const float* surprise_scale      = (const float*)d_in[25];
    const float* surprise_bias       = (const float*)d_in[26];
    const float* resonance_scale     = (const float*)d_in[27];
    const float* resonance_threshold = (const float*)d_in[28];
    const float* ltm_weight = (const float*)d_in[29];
    const float* pos_freqs  = (const float*)d_in[30];
    const float* ltm_mem    = (const float*)d_in[31];  // complex64 interleaved (16,256)
    const float* ltm_count  = (const float*)d_in[32];

    float* ws  = (float*)d_ws;
    float* Hf  = ws;                    // region sized NT*896 floats (holds Hhi+Hlo bf16)
    float* V   = Hf  + (size_t)NT * HCOLS;
    float* Fk  = V   + (size_t)NT * DD;
    float* Fq  = Fk  + (size_t)NT * FDIM;
    float* Fql = Fq  + (size_t)NT * FDIM;
    float* Tot = Fql + (size_t)NT * 32;                  // region reserved (unused)
    float* J   = Tot + (size_t)NT * DD;                  // 8*NT f32 (compact joint phasors)
    __hip_bfloat16* W2T = (__hip_bfloat16*)(J + (size_t)NT * 8);   // 4*16*768 bf16
    float* wg  = (float*)(W2T + 4 * 16 * 768);           // NT f32
    __hip_bfloat16* OWT = (__hip_bfloat16*)(wg + NT);    // 256*768 bf16

    // H region as bf16 hi/lo (same byte footprint as fp32 H)
    __hip_bfloat16* Hhi = (__hip_bfloat16*)Hf;           // NT*896 bf16
    __hip_bfloat16* Hlo = Hhi + (size_t)NT * HCOLS;      // NT*896 bf16
    // chunk states alias H region (dead after k2): S+M = 2.62M floats < NT*896 = 3.67M
    float* S   = Hf;
    float* M   = Hf + (size_t)NC * SST;
    // LN-split output aliases S (dead after k4b; Hn = 1.05M floats < 1.31M, below M)
    __hip_bfloat16* Hnhi = (__hip_bfloat16*)Hf;          // NT*256 bf16
    __hip_bfloat16* Hnlo = Hnhi + (size_t)NT * DD;       // NT*256 bf16
    // first-layer prep buffers alias [Fk .. Tot) region (dead until k2 writes it)
    __hip_bfloat16* xhi = (__hip_bfloat16*)Fk;           // NT*DD bf16
    __hip_bfloat16* xlo = xhi + (size_t)NT * DD;         // NT*DD bf16
    __hip_bfloat16* BT  = xlo + (size_t)NT * DD;         // 1152*768 bf16
    float* bcat = (float*)(BT + (size_t)NCOLS * KBIG);   // 1152 f32

    k0_prep<<<K0A_BLKS + K0B_BLKS + K0C_BLKS + K0D_BLKS, 256, 0, stream>>>(
        x, ke_w1, ke_b1, qe_w1, qe_b1, lke_w1, lke_b1, gate_w1, gate_b1, v_w, v_b,
        ke_w2, qe_w2, lke_w2, gate_w2, out_w, xhi, xlo, BT, bcat, W2T, OWT);
    k1_mfma<<<dim3(NT / 128, NCOLS / 128), 256, 0, stream>>>(xhi, xlo, BT, bcat,
                                                             Hhi, Hlo, V);
    k2_fused<<<NT / 16, 256, 0, stream>>>(Hhi, Hlo, W2T,
                                          ke_b2, qe_b2, lke_b2, gate_b2,
                                          set_weights, pos_weight,
                                          ltm_weight, ltm_count, pos_freqs,
                                          Fk, Fq, Fql, J);
    k3a_scan<<<BB, 512, 0, stream>>>(J, wg, resonance_scale, resonance_threshold,
                                     surprise_scale, surprise_bias);
    k4a_state<<<dim3(NC, 4), 256, 0, stream>>>(Fk, wg, V, S);
    k4b_scan<<<dim3(SST / 256, BB), 256, 0, stream>>>(S, M);
    k4c_ln<<<dim3(NC, 8), 256, 0, stream>>>(Fq, Fk, wg, Fql, V, M, ltm_mem,
                                            out_ln_g, out_ln_b, Hnhi, Hnlo);
    k5b_mfma<<<dim3(NT / 64, DD / 64), 256, 0, stream>>>(Hnhi, Hnlo, OWT, out_b,
                                                         (float*)d_out);
}

// Round 15
// 116.715 us; speedup vs baseline: 1.0853x; 1.0853x over previous
//
#include <hip/hip_runtime.h>
#include <hip/hip_bf16.h>
#include <math.h>

#define BB 2
#define LL 2048
#define DD 256
#define NT (BB*LL)      // 4096 tokens
#define HCOLS 896       // ke(256) qe(256) lke(256) gate(128)
#define NCOLS 1152      // HCOLS + v(256)
#define KBIG 768        // split-bf16 concat K: [hi|lo-cross|hi-cross]
#define FDIM 80         // 32 bank + 8 joint + 32 pos + 8 pad
#define CC 64           // chunk length
#define NC (NT/CC)      // 64 chunks
#define NCB (LL/CC)     // 32 chunks per batch
#define SST (FDIM*DD)   // 20480 floats per chunk state
#define PI_F 3.14159265358979323846f

typedef __attribute__((ext_vector_type(8))) short s8frag;
typedef __attribute__((ext_vector_type(4))) float f4acc;

// global_load_lds 16B: LDS dest = uniform base + lane*16 (linear); global src per-lane.
#define GLDS16(g, l) __builtin_amdgcn_global_load_lds( \
    (const __attribute__((address_space(1))) void*)(g), \
    (__attribute__((address_space(3))) void*)(l), 16, 0, 0)

__device__ __forceinline__ float gelu_erf(float v) {
    return 0.5f * v * (1.0f + erff(v * 0.70710678118654752440f));
}
__device__ __forceinline__ float sigmoidf_(float v) {
    return 1.0f / (1.0f + expf(-v));
}

// ---------------- K0: fused prep (x hi/lo | BT+OWT transpose tiles | W2T | bias)
#define K0A_BLKS (NT * DD / 4 / 256)          // 1024
#define K0B_TW   22                           // 18 BT tiles + 4 OWT tiles per k-row
#define K0B_BLKS ((KBIG / 64) * K0B_TW)       // 12*22 = 264
#define K0C_BLKS (4 * 16 * 768 / 256)         // 192
#define K0D_BLKS 5                            // bias (1152 cols)
__global__ __launch_bounds__(256) void k0_prep(
    const float* __restrict__ x,
    const float* __restrict__ ke_w1, const float* __restrict__ ke_b1,
    const float* __restrict__ qe_w1, const float* __restrict__ qe_b1,
    const float* __restrict__ lke_w1, const float* __restrict__ lke_b1,
    const float* __restrict__ gate_w1, const float* __restrict__ gate_b1,
    const float* __restrict__ v_w, const float* __restrict__ v_b,
    const float* __restrict__ ke_w2, const float* __restrict__ qe_w2,
    const float* __restrict__ lke_w2, const float* __restrict__ gate_w2,
    const float* __restrict__ out_w,
    __hip_bfloat16* __restrict__ xhi, __hip_bfloat16* __restrict__ xlo,
    __hip_bfloat16* __restrict__ BT, float* __restrict__ bcat,
    __hip_bfloat16* __restrict__ W2T, __hip_bfloat16* __restrict__ OWT)
{
    __shared__ float tile[64][65];
    const int b = blockIdx.x, tid = threadIdx.x;
    if (b < K0A_BLKS) {
        int idx = b * 256 + tid;
        float4 v = reinterpret_cast<const float4*>(x)[idx];
        float vv[4] = {v.x, v.y, v.z, v.w};
        #pragma unroll
        for (int j = 0; j < 4; ++j) {
            __hip_bfloat16 h = __float2bfloat16(vv[j]);
            xhi[idx * 4 + j] = h;
            xlo[idx * 4 + j] = __float2bfloat16(vv[j] - __bfloat162float(h));
        }
    } else if (b < K0A_BLKS + K0B_BLKS) {
        int bb = b - K0A_BLKS;
        int bk = bb / K0B_TW, bn = bb - bk * K0B_TW;
        int kp0 = bk * 64, n0 = bn * 64;
        int seg = kp0 >> 8;
        int k0 = kp0 - seg * 256;
        #pragma unroll 4
        for (int i = 0; i < 16; ++i) {
            int kl = i * 4 + (tid >> 6);
            int nl = tid & 63;
            int k = k0 + kl, n = n0 + nl;
            float w;
            if (n < 256)       w = ke_w1[k * 256 + n];
            else if (n < 512)  w = qe_w1[k * 256 + (n - 256)];
            else if (n < 768)  w = lke_w1[k * 256 + (n - 512)];
            else if (n < 896)  w = gate_w1[k * 128 + (n - 768)];
            else if (n < 1152) w = v_w[k * 256 + (n - 896)];
            else               w = out_w[k * 256 + (n - 1152)];
            tile[kl][nl] = w;
        }
        __syncthreads();
        #pragma unroll 4
        for (int i = 0; i < 16; ++i) {
            int nl = i * 4 + (tid >> 6);
            int kpl = tid & 63;
            float w = tile[kpl][nl];
            __hip_bfloat16 hi = __float2bfloat16(w);
            __hip_bfloat16 out = (seg == 1)
                ? __float2bfloat16(w - __bfloat162float(hi)) : hi;
            if (n0 < 1152)
                BT[(size_t)(n0 + nl) * KBIG + kp0 + kpl] = out;
            else
                OWT[(size_t)(n0 + nl - 1152) * KBIG + kp0 + kpl] = out;
        }
    } else if (b < K0A_BLKS + K0B_BLKS + K0C_BLKS) {
        int idx = (b - K0A_BLKS - K0B_BLKS) * 256 + tid;  // over 4*16*768
        int g = idx / (16 * 768);
        int rem = idx - g * (16 * 768);
        int n = rem / 768;
        int kp = rem - n * 768;
        float w = 0.0f;
        int seg;
        if (g < 3) {
            seg = kp >> 8;
            int k = kp & 255;
            const float* W = (g == 0) ? ke_w2 : (g == 1) ? qe_w2 : lke_w2;
            w = W[k * 16 + n];
        } else {
            seg = kp >> 7;
            int k = kp & 127;
            if (n == 0 && kp < 384) w = gate_w2[k];
            else { seg = 0; w = 0.0f; }
        }
        __hip_bfloat16 hi = __float2bfloat16(w);
        __hip_bfloat16 out = (seg == 1) ? __float2bfloat16(w - __bfloat162float(hi)) : hi;
        W2T[idx] = out;
    } else {
        int n = (b - K0A_BLKS - K0B_BLKS - K0C_BLKS) * 256 + tid;
        if (n < NCOLS) {
            float bia;
            if (n < 256)      bia = ke_b1[n];
            else if (n < 512) bia = qe_b1[n - 256];
            else if (n < 768) bia = lke_b1[n - 512];
            else if (n < 896) bia = gate_b1[n - 768];
            else              bia = v_b[n - 896];
            bcat[n] = bia;
        }
    }
}

// ---------------- K1: MFMA GEMM  C[4096][1152] = A[4096][768] @ B[768][1152]
// 128x64 tile, BK=64, SINGLE-buffered (24KB LDS -> 6 blocks/CU; TLP hides staging).
__global__ __launch_bounds__(256) void k1_mfma(
    const __hip_bfloat16* __restrict__ xhi, const __hip_bfloat16* __restrict__ xlo,
    const __hip_bfloat16* __restrict__ BT, const float* __restrict__ bcat,
    __hip_bfloat16* __restrict__ Hhi, __hip_bfloat16* __restrict__ Hlo,
    float* __restrict__ V)
{
    __shared__ __align__(16) short As[128 * 64];
    __shared__ __align__(16) short Bs[64 * 64];
    const int tid = threadIdx.x;
    const int wave = tid >> 6, lane = tid & 63;
    const int wr = wave >> 1, wc = wave & 1;
    const int bm = blockIdx.x, bn = blockIdx.y;
    const int lg = lane >> 4, lr = lane & 15;

    f4acc acc[4][2] = {};

    for (int kt = 0; kt < KBIG / 64; ++kt) {
        const int k0 = kt * 64;
        const __hip_bfloat16* xsrc = (kt < 8) ? xhi : xlo;
        const int kcol = (kt < 8) ? (k0 & 255) : (k0 - 512);
        #pragma unroll
        for (int j = 0; j < 4; ++j) {        // A: rows wave*32 .. +32
            int r0 = wave * 32 + j * 8;
            int row = r0 + (lane >> 3);
            int ch = (lane & 7) ^ (row & 7);
            GLDS16(xsrc + (size_t)(bm * 128 + row) * DD + kcol + ch * 8, &As[r0 * 64]);
        }
        #pragma unroll
        for (int j = 0; j < 2; ++j) {        // B: rows wave*16 .. +16
            int r0 = wave * 16 + j * 8;
            int row = r0 + (lane >> 3);
            int ch = (lane & 7) ^ (row & 7);
            GLDS16(BT + (size_t)(bn * 64 + row) * KBIG + k0 + ch * 8, &Bs[r0 * 64]);
        }
        __syncthreads();
        #pragma unroll
        for (int kk = 0; kk < 2; ++kk) {
            s8frag a[4], b[2];
            #pragma unroll
            for (int i = 0; i < 4; ++i) {
                int arow = wr * 64 + i * 16 + lr;
                int slot = (kk * 4 + lg) ^ (arow & 7);
                a[i] = *reinterpret_cast<const s8frag*>(&As[arow * 64 + slot * 8]);
            }
            #pragma unroll
            for (int i = 0; i < 2; ++i) {
                int brow = wc * 32 + i * 16 + lr;
                int slot = (kk * 4 + lg) ^ (brow & 7);
                b[i] = *reinterpret_cast<const s8frag*>(&Bs[brow * 64 + slot * 8]);
            }
            #pragma unroll
            for (int mi = 0; mi < 4; ++mi)
                #pragma unroll
                for (int ni = 0; ni < 2; ++ni)
                    acc[mi][ni] = __builtin_amdgcn_mfma_f32_16x16x32_bf16(
                        a[mi], b[ni], acc[mi][ni], 0, 0, 0);
        }
        __syncthreads();
    }

    #pragma unroll
    for (int ni = 0; ni < 2; ++ni) {
        int n = bn * 64 + wc * 32 + ni * 16 + lr;
        float bia = bcat[n];
        #pragma unroll
        for (int mi = 0; mi < 4; ++mi) {
            #pragma unroll
            for (int r = 0; r < 4; ++r) {
                int m = bm * 128 + wr * 64 + mi * 16 + lg * 4 + r;
                float v = acc[mi][ni][r] + bia;
                if (n < HCOLS) {
                    float hv = gelu_erf(v);
                    __hip_bfloat16 h = __float2bfloat16(hv);
                    Hhi[(size_t)m * HCOLS + n] = h;
                    Hlo[(size_t)m * HCOLS + n] = __float2bfloat16(hv - __bfloat162float(h));
                } else {
                    V[(size_t)m * DD + (n - HCOLS)] = v;
                }
            }
        }
    }
}

// ---------------- K2: fused second-layer MFMA + phases + features (16 tokens/block)
__global__ __launch_bounds__(256) void k2_fused(
    const __hip_bfloat16* __restrict__ Hhi, const __hip_bfloat16* __restrict__ Hlo,
    const __hip_bfloat16* __restrict__ W2T,
    const float* __restrict__ ke_b2, const float* __restrict__ qe_b2,
    const float* __restrict__ lke_b2, const float* __restrict__ gate_b2,
    const float* __restrict__ set_weights, const float* __restrict__ pos_weight,
    const float* __restrict__ ltm_weight, const float* __restrict__ ltm_count,
    const float* __restrict__ pos_freqs,
    float* __restrict__ Fk, float* __restrict__ Fq, float* __restrict__ Fql,
    float* __restrict__ J)
{
    __shared__ float c2s[16][52];   // activated phases: cols 0..48 used
    const int tid = threadIdx.x;
    const int g = tid >> 6, lane = tid & 63;
    const int lg = lane >> 4, lr = lane & 15;
    const int t0 = blockIdx.x * 16;

    {
        const int seglen = (g < 3) ? 256 : 128;
        const int gbase = (g < 3) ? g * 256 : 768;
        const int nsteps = (g < 3) ? 24 : 12;
        const __hip_bfloat16* wbase = W2T + (size_t)(g * 16 + lr) * 768;
        f4acc acc = {};
        for (int kt = 0; kt < nsteps; ++kt) {
            const int kp = kt * 32;
            const int seg = kp / seglen;
            const int kk = kp - seg * seglen;
            const __hip_bfloat16* asrc = (seg < 2) ? Hhi : Hlo;
            s8frag b = *reinterpret_cast<const s8frag*>(wbase + kp + lg * 8);
            s8frag a = *reinterpret_cast<const s8frag*>(
                asrc + (size_t)(t0 + lr) * HCOLS + gbase + kk + lg * 8);
            acc = __builtin_amdgcn_mfma_f32_16x16x32_bf16(a, b, acc, 0, 0, 0);
        }
        int col = g * 16 + lr;
        if (col < 49) {
            #pragma unroll
            for (int r = 0; r < 4; ++r)
                c2s[lg * 4 + r][col] = acc[r];
        }
    }
    __syncthreads();

    for (int i = tid; i < 16 * 64; i += 256) {
        int t = i >> 6, c = i & 63;
        if (c < 49) {
            float a = c2s[t][c];
            float val;
            if (c < 16)      val = tanhf(a + ke_b2[c]) * PI_F;
            else if (c < 32) val = tanhf(a + qe_b2[c - 16]) * PI_F;
            else if (c < 48) val = tanhf(a + lke_b2[c - 32]) * PI_F;
            else             val = sigmoidf_(a + gate_b2[0]);
            c2s[t][c] = val;
        }
    }
    __syncthreads();

    float sw[4];
    {
        float s0 = set_weights[0], s1 = set_weights[1], s2 = set_weights[2], s3 = set_weights[3];
        float mx = fmaxf(fmaxf(s0, s1), fmaxf(s2, s3));
        float e0 = expf(s0 - mx), e1 = expf(s1 - mx), e2 = expf(s2 - mx), e3 = expf(s3 - mx);
        float inv = 1.0f / (e0 + e1 + e2 + e3);
        sw[0] = e0 * inv; sw[1] = e1 * inv; sw[2] = e2 * inv; sw[3] = e3 * inv;
    }
    const float spw = sigmoidf_(pos_weight[0]);
    const float altm = sigmoidf_(ltm_weight[0]) / sqrtf(fmaxf(ltm_count[0], 1.0f) * 16.0f);
    const int sg = tid >> 5, sl = tid & 31;

    for (int tr = 0; tr < 2; ++tr) {
        const int lt = tr * 8 + sg;
        const int t = t0 + lt;
        const float gg = c2s[lt][48];
        const float aq = gg * 0.2f;
        const float apos = (1.0f - gg) * spw;
        const int l = t & (LL - 1);
        float* fkr  = Fk  + (size_t)t * FDIM;
        float* fqr  = Fq  + (size_t)t * FDIM;
        float* fqlr = Fql + (size_t)t * 32;

        if (sl < 16) {
            int p = sl;
            float sk, ck; sincosf(c2s[lt][p], &sk, &ck);
            fkr[2 * p] = ck; fkr[2 * p + 1] = sk;
            float sq, cq; sincosf(c2s[lt][16 + p], &sq, &cq);
            float wq = aq * sw[p >> 2];
            fqr[2 * p] = wq * cq; fqr[2 * p + 1] = wq * sq;
            float sl_, cl_; sincosf(c2s[lt][32 + p], &sl_, &cl_);
            fqlr[2 * p] = altm * cl_; fqlr[2 * p + 1] = altm * sl_;
            float th = (float)l * pos_freqs[p] * (2.0f * PI_F);
            float sp, cp; sincosf(th, &sp, &cp);
            fkr[40 + 2 * p] = cp; fkr[41 + 2 * p] = sp;
            fqr[40 + 2 * p] = apos * cp; fqr[41 + 2 * p] = apos * sp;
        } else if (sl < 20) {
            int p = sl - 16;
            float pjk = c2s[lt][p] + c2s[lt][p + 4] + c2s[lt][p + 8] + c2s[lt][p + 12];
            float pjq = c2s[lt][16 + p] + c2s[lt][20 + p] + c2s[lt][24 + p] + c2s[lt][28 + p];
            float sjk, cjk; sincosf(pjk, &sjk, &cjk);
            float sjq, cjq; sincosf(pjq, &sjq, &cjq);
            fkr[32 + 2 * p] = cjk; fkr[33 + 2 * p] = sjk;
            fqr[32 + 2 * p] = aq * cjq; fqr[33 + 2 * p] = aq * sjq;
            J[(size_t)(2 * p) * NT + t] = cjk;
            J[(size_t)(2 * p + 1) * NT + t] = sjk;
        } else if (sl < 24) {
            int p = sl - 20;
            fkr[72 + 2 * p] = 0.0f; fkr[73 + 2 * p] = 0.0f;
            fqr[72 + 2 * p] = 0.0f; fqr[73 + 2 * p] = 0.0f;
        }
    }
}

// ---------------- K3a: exclusive scan of joint-key phasors (from compact J) -> wg[token]
__device__ __forceinline__ int swz2048(int l) {
    return (l & ~31) | ((l ^ (l >> 5)) & 31);
}
__global__ __launch_bounds__(512) void k3a_scan(
    const float* __restrict__ J, float* __restrict__ wg,
    const float* __restrict__ resonance_scale, const float* __restrict__ resonance_threshold,
    const float* __restrict__ surprise_scale, const float* __restrict__ surprise_bias)
{
    __shared__ float km[8 * LL];
    const int b = blockIdx.x;
    const int tid = threadIdx.x;
    const int w = tid >> 6;     // series 0..7
    const int lane = tid & 63;
    {
        float v[32];
        float s = 0.0f;
        int l0 = lane * 32;
        const float4* src = reinterpret_cast<const float4*>(
            J + (size_t)w * NT + b * LL + l0);
        #pragma unroll
        for (int i = 0; i < 8; ++i) {
            float4 q = src[i];
            v[4 * i + 0] = q.x; v[4 * i + 1] = q.y;
            v[4 * i + 2] = q.z; v[4 * i + 3] = q.w;
            s += q.x + q.y + q.z + q.w;
        }
        float local = s;
        #pragma unroll
        for (int off = 1; off < 64; off <<= 1) {
            float n = __shfl_up(s, off);
            if (lane >= off) s += n;
        }
        float run = s - local;   // exclusive base
        #pragma unroll 4
        for (int i = 0; i < 32; ++i) { km[w * LL + swz2048(l0 + i)] = run; run += v[i]; }
    }
    __syncthreads();
    const float sc  = fminf(fmaxf(resonance_scale[0], 1.0f), 20.0f);
    const float th  = fminf(fmaxf(resonance_threshold[0], 0.1f), 0.9f);
    const float ssc = surprise_scale[0];
    const float sbi = surprise_bias[0];
    for (int q = 0; q < 4; ++q) {
        int l = tid + 512 * q;
        int ls = swz2048(l);
        float rm = 0.0f;
        #pragma unroll
        for (int p = 0; p < 4; ++p) {
            float re = km[(2 * p) * LL + ls], im = km[(2 * p + 1) * LL + ls];
            rm += sqrtf(re * re + im * im);
        }
        rm *= 0.25f;
        float nr = rm / sqrtf(fmaxf((float)l, 1.0f));
        float sur = 0.5f * (1.0f - tanhf(sc * (nr - th)));
        wg[b * LL + l] = sigmoidf_(ssc * (sur - 0.5f) + sbi);
    }
}

// ---------------- K4a: per-chunk key state S_c = (gated F_k_c)^T @ V_c   (80 x 256)
__global__ __launch_bounds__(256) void k4a_state(
    const float* __restrict__ Fk, const float* __restrict__ wg,
    const float* __restrict__ V, float* __restrict__ S)
{
    __shared__ __align__(16) float fk[CC][FDIM];
    const int c = blockIdx.x;
    const int f0 = blockIdx.y * 20;       // f quarter
    const int tid = threadIdx.x;          // = output dim d
    for (int i = tid; i < CC * FDIM; i += 256) {
        int r = i / FDIM, cx = i - r * FDIM;
        float f = Fk[(size_t)c * CC * FDIM + i];
        if (cx < 40) f *= wg[c * CC + r];   // fused write-gate (dims 0..39)
        fk[r][cx] = f;
    }
    __syncthreads();
    float acc[20];
    #pragma unroll
    for (int f = 0; f < 20; ++f) acc[f] = 0.0f;
    const float* vp = V + (size_t)c * CC * DD + tid;
    for (int r = 0; r < CC; ++r) {
        float v = vp[(size_t)r * DD];
        #pragma unroll
        for (int g = 0; g < 5; ++g) {
            float4 q = *reinterpret_cast<const float4*>(&fk[r][f0 + 4 * g]);
            acc[4 * g + 0] += q.x * v; acc[4 * g + 1] += q.y * v;
            acc[4 * g + 2] += q.z * v; acc[4 * g + 3] += q.w * v;
        }
    }
    float* sp = S + (size_t)c * SST + tid;
    #pragma unroll
    for (int f = 0; f < 20; ++f) sp[(size_t)(f0 + f) * DD] = acc[f];
}

// ---------------- K4b: exclusive prefix-sum of chunk states (full-register ILP)
__global__ __launch_bounds__(256) void k4b_scan(
    const float* __restrict__ S, float* __restrict__ M)
{
    const int e = blockIdx.x * 256 + threadIdx.x;   // element in [0, SST)
    const int b = blockIdx.y;
    const float* sp = S + (size_t)(b * NCB) * SST + e;
    float* mp = M + (size_t)(b * NCB) * SST + e;
    float v[NCB];
    #pragma unroll
    for (int cc = 0; cc < NCB; ++cc) v[cc] = sp[(size_t)cc * SST];  // 32 indep loads
    float run = 0.0f;
    #pragma unroll
    for (int cc = 0; cc < NCB; ++cc) { float t = v[cc]; v[cc] = run; run += t; }
    #pragma unroll
    for (int cc = 0; cc < NCB; ++cc) mp[(size_t)cc * SST] = v[cc];
}

// ---------------- K4c: retrieval + LTM + fused LayerNorm -> bf16 hi/lo split
// grid (NC, 8): 8-row slices, 512 blocks (2/CU). Emits Hnhi/Hnlo.
__global__ __launch_bounds__(256) void k4c_ln(
    const float* __restrict__ Fq, const float* __restrict__ Fk,
    const float* __restrict__ wg, const float* __restrict__ Fql,
    const float* __restrict__ V, const float* __restrict__ M,
    const float* __restrict__ ltm_mem,
    const float* __restrict__ gln, const float* __restrict__ bln,
    __hip_bfloat16* __restrict__ Hnhi, __hip_bfloat16* __restrict__ Hnlo)
{
    __shared__ __align__(16) float fq[8][FDIM];
    __shared__ __align__(16) float fkS[CC * 96];   // swizzled: [r][cx ^ ((r&7)<<2)]
    __shared__ __align__(16) float sc[8][68];
    const int c = blockIdx.x;
    const int h = blockIdx.y;
    const int r0 = h * 8;
    const int nrows = r0 + 8;           // causal extent of needed k rows
    const int tid = threadIdx.x;
    const int wave = tid >> 6, lane = tid & 63;

    for (int i = tid; i < 8 * FDIM; i += 256) {
        int r = i / FDIM, cx = i - r * FDIM;
        fq[r][cx] = Fq[(size_t)(c * CC + r0 + r) * FDIM + cx];
    }
    for (int i = tid; i < nrows * FDIM; i += 256) {
        int r = i / FDIM, cx = i - r * FDIM;
        float f = Fk[(size_t)c * CC * FDIM + i];
        if (cx < 40) f *= wg[c * CC + r];   // fused write-gate
        fkS[r * 96 + (cx ^ ((r & 7) << 2))] = f;
    }
    __syncthreads();

    #pragma unroll
    for (int q = 0; q < 2; ++q) {
        int idx = tid + 256 * q;
        int i = idx >> 6, j = idx & 63;
        float s = 0.0f;
        if (r0 + i >= j) {
            const int sw = (j & 7) << 2;
            #pragma unroll
            for (int g = 0; g < 20; ++g) {
                float4 a = *reinterpret_cast<const float4*>(&fq[i][4 * g]);
                float4 b = *reinterpret_cast<const float4*>(&fkS[j * 96 + ((4 * g) ^ sw)]);
                s += a.x * b.x + a.y * b.y + a.z * b.z + a.w * b.w;
            }
        }
        sc[i][j] = s;
    }
    __syncthreads();

    const int d = tid;
    float acc[8];
    #pragma unroll
    for (int i = 0; i < 8; ++i) acc[i] = 0.0f;

    const float* mp = M + (size_t)c * SST + d;
    #pragma unroll 2
    for (int g = 0; g < 20; ++g) {
        float m0 = mp[(size_t)(4 * g + 0) * DD];
        float m1 = mp[(size_t)(4 * g + 1) * DD];
        float m2 = mp[(size_t)(4 * g + 2) * DD];
        float m3 = mp[(size_t)(4 * g + 3) * DD];
        #pragma unroll
        for (int i = 0; i < 8; ++i) {
            float4 a = *reinterpret_cast<const float4*>(&fq[i][4 * g]);
            acc[i] += a.x * m0 + a.y * m1 + a.z * m2 + a.w * m3;
        }
    }
    const float* vp = V + (size_t)c * CC * DD + d;
    const int j4max = nrows >> 2;
    #pragma unroll 2
    for (int j4 = 0; j4 < j4max; ++j4) {
        float v0 = vp[(size_t)(4 * j4 + 0) * DD];
        float v1 = vp[(size_t)(4 * j4 + 1) * DD];
        float v2 = vp[(size_t)(4 * j4 + 2) * DD];
        float v3 = vp[(size_t)(4 * j4 + 3) * DD];
        #pragma unroll
        for (int i = 0; i < 8; ++i) {
            float4 s4 = *reinterpret_cast<const float4*>(&sc[i][4 * j4]);
            acc[i] += s4.x * v0 + s4.y * v1 + s4.z * v2 + s4.w * v3;
        }
    }
    // LTM epilogue
    float mre[16], mim[16];
    #pragma unroll
    for (int p = 0; p < 16; ++p) {
        mre[p] = ltm_mem[((size_t)p * DD + d) * 2];
        mim[p] = ltm_mem[((size_t)p * DD + d) * 2 + 1];
    }
    __syncthreads();
    {
        int r = tid >> 5, p = tid & 31;
        sc[r][p] = Fql[(size_t)(c * CC + r0 + r) * 32 + p];
    }
    __syncthreads();
    #pragma unroll
    for (int i = 0; i < 8; ++i) {
        float a = acc[i];
        #pragma unroll
        for (int p = 0; p < 16; ++p)
            a += sc[i][2 * p] * mre[p] + sc[i][2 * p + 1] * mim[p];
        acc[i] = a;
    }
    __syncthreads();

    // fused LayerNorm per row: wave shfl reduce + cross-wave via sc
    #pragma unroll
    for (int i = 0; i < 8; ++i) {
        float s = acc[i], s2 = acc[i] * acc[i];
        #pragma unroll
        for (int off = 1; off < 64; off <<= 1) {
            s  += __shfl_xor(s, off);
            s2 += __shfl_xor(s2, off);
        }
        if (lane == 0) { sc[i][wave] = s; sc[i][4 + wave] = s2; }
    }
    __syncthreads();
    const float gv = gln[d], bv = bln[d];
    __hip_bfloat16* hp = Hnhi + (size_t)(c * CC + r0) * DD + d;
    __hip_bfloat16* lp = Hnlo + (size_t)(c * CC + r0) * DD + d;
    #pragma unroll 1
    for (int i = 0; i < 8; ++i) {
        float s  = sc[i][0] + sc[i][1] + sc[i][2] + sc[i][3];
        float s2 = sc[i][4] + sc[i][5] + sc[i][6] + sc[i][7];
        float mu = s * (1.0f / 256.0f);
        float var = s2 * (1.0f / 256.0f) - mu * mu;
        float rstd = rsqrtf(var + 1e-5f);
        float hn = (acc[i] - mu) * rstd * gv + bv;
        __hip_bfloat16 hb = __float2bfloat16(hn);
        hp[(size_t)i * DD] = hb;
        lp[(size_t)i * DD] = __float2bfloat16(hn - __bfloat162float(hb));
    }
}

// ---------------- K5b: MFMA GEMM  out[4096][256] = [Hnhi|Hnhi|Hnlo] @ OWT^T + out_b
__global__ __launch_bounds__(256) void k5b_mfma(
    const __hip_bfloat16* __restrict__ Hnhi, const __hip_bfloat16* __restrict__ Hnlo,
    const __hip_bfloat16* __restrict__ OWT, const float* __restrict__ out_b,
    float* __restrict__ out)
{
    __shared__ __align__(16) short As[64 * 64];
    __shared__ __align__(16) short Bs[64 * 64];
    const int tid = threadIdx.x;
    const int wave = tid >> 6, lane = tid & 63;
    const int wr = wave >> 1, wc = wave & 1;
    const int bm = blockIdx.x, bn = blockIdx.y;
    const int lg = lane >> 4, lr = lane & 15;

    f4acc acc[2][2] = {};

    for (int kt = 0; kt < KBIG / 64; ++kt) {
        const int k0 = kt * 64;
        const __hip_bfloat16* asrc = (kt < 8) ? Hnhi : Hnlo;
        const int kcol = (kt < 8) ? (k0 & 255) : (k0 - 512);
        #pragma unroll
        for (int j = 0; j < 2; ++j) {
            int r0 = wave * 16 + j * 8;
            int row = r0 + (lane >> 3);
            int ch = (lane & 7) ^ (row & 7);
            GLDS16(asrc + (size_t)(bm * 64 + row) * DD + kcol + ch * 8, &As[r0 * 64]);
            GLDS16(OWT + (size_t)(bn * 64 + row) * KBIG + k0 + ch * 8, &Bs[r0 * 64]);
        }
        __syncthreads();
        #pragma unroll
        for (int kk = 0; kk < 2; ++kk) {
            s8frag a[2], b[2];
            #pragma unroll
            for (int i = 0; i < 2; ++i) {
                int arow = wr * 32 + i * 16 + lr;
                int aslot = (kk * 4 + lg) ^ (arow & 7);
                a[i] = *reinterpret_cast<const s8frag*>(&As[arow * 64 + aslot * 8]);
                int brow = wc * 32 + i * 16 + lr;
                int bslot = (kk * 4 + lg) ^ (brow & 7);
                b[i] = *reinterpret_cast<const s8frag*>(&Bs[brow * 64 + bslot * 8]);
            }
            #pragma unroll
            for (int mi = 0; mi < 2; ++mi)
                #pragma unroll
                for (int ni = 0; ni < 2; ++ni)
                    acc[mi][ni] = __builtin_amdgcn_mfma_f32_16x16x32_bf16(
                        a[mi], b[ni], acc[mi][ni], 0, 0, 0);
        }
        __syncthreads();
    }

    #pragma unroll
    for (int ni = 0; ni < 2; ++ni) {
        int n = bn * 64 + wc * 32 + ni * 16 + lr;
        float ob = out_b[n];
        #pragma unroll
        for (int mi = 0; mi < 2; ++mi) {
            #pragma unroll
            for (int r = 0; r < 4; ++r) {
                int m = bm * 64 + wr * 32 + mi * 16 + lg * 4 + r;
                out[(size_t)m * DD + n] = acc[mi][ni][r] + ob;
            }
        }
    }
}

extern "C" void kernel_launch(void* const* d_in, const int* in_sizes, int n_in,
                              void* d_out, int out_size, void* d_ws, size_t ws_size,
                              hipStream_t stream)
{
    (void)in_sizes; (void)n_in; (void)out_size; (void)ws_size;
    const float* x        = (const float*)d_in[0];
    const float* ke_w1    = (const float*)d_in[1];
    const float* ke_b1    = (const float*)d_in[2];
    const float* ke_w2    = (const float*)d_in[3];
    const float* ke_b2    = (const float*)d_in[4];
    const float* qe_w1    = (const float*)d_in[5];
    const float* qe_b1    = (const float*)d_in[6];
    const float* qe_w2    = (const float*)d_in[7];
    const float* qe_b2    = (const float*)d_in[8];
    const float* v_w      = (const float*)d_in[9];
    const float* v_b      = (const float*)d_in[10];
    const float* out_ln_g = (const float*)d_in[11];
    const float* out_ln_b = (const float*)d_in[12];
    const float* out_w    = (const float*)d_in[13];
    const float* out_b    = (const float*)d_in[14];
    const float* set_weights = (const float*)d_in[15];
    const float* pos_weight  = (const float*)d_in[16];
    const float* gate_w1  = (const float*)d_in[17];
    const float* gate_b1  = (const float*)d_in[18];
    const float* gate_w2  = (const float*)d_in[19];
    const float* gate_b2  = (const float*)d_in[20];
    const float* lke_w1   = (const float*)d_in[21];
    const float* lke_b1   = (const float*)d_in[22];
    const float* lke_w2   = (const float*)d_in[23];
    const float* lke_b2   = (const float*)d_in[24];
    const float* surprise_scale      = (const float*)d_in[25];
    const float* surprise_bias       = (const float*)d_in[26];
    const float* resonance_scale     = (const float*)d_in[27];
    const float* resonance_threshold = (const float*)d_in[28];
    const float* ltm_weight = (const float*)d_in[29];
    const float* pos_freqs  = (const float*)d_in[30];
    const float* ltm_mem    = (const float*)d_in[31];  // complex64 interleaved (16,256)
    const float* ltm_count  = (const float*)d_in[32];

    float* ws  = (float*)d_ws;
    float* Hf  = ws;                    // region sized NT*896 floats (holds Hhi+Hlo bf16)
    float* V   = Hf  + (size_t)NT * HCOLS;
    float* Fk  = V   + (size_t)NT * DD;
    float* Fq  = Fk  + (size_t)NT * FDIM;
    float* Fql = Fq  + (size_t)NT * FDIM;
    float* Tot = Fql + (size_t)NT * 32;                  // region reserved (unused)
    float* J   = Tot + (size_t)NT * DD;                  // 8*NT f32 (compact joint phasors)
    __hip_bfloat16* W2T = (__hip_bfloat16*)(J + (size_t)NT * 8);   // 4*16*768 bf16
    float* wg  = (float*)(W2T + 4 * 16 * 768);           // NT f32
    __hip_bfloat16* OWT = (__hip_bfloat16*)(wg + NT);    // 256*768 bf16

    // H region as bf16 hi/lo (same byte footprint as fp32 H)
    __hip_bfloat16* Hhi = (__hip_bfloat16*)Hf;           // NT*896 bf16
    __hip_bfloat16* Hlo = Hhi + (size_t)NT * HCOLS;      // NT*896 bf16
    // chunk states alias H region (dead after k2): S+M = 2.62M floats < NT*896 = 3.67M
    float* S   = Hf;
    float* M   = Hf + (size_t)NC * SST;
    // LN-split output aliases S (dead after k4b; Hn = 1.05M floats < 1.31M, below M)
    __hip_bfloat16* Hnhi = (__hip_bfloat16*)Hf;          // NT*256 bf16
    __hip_bfloat16* Hnlo = Hnhi + (size_t)NT * DD;       // NT*256 bf16
    // first-layer prep buffers alias [Fk .. Tot) region (dead until k2 writes it)
    __hip_bfloat16* xhi = (__hip_bfloat16*)Fk;           // NT*DD bf16
    __hip_bfloat16* xlo = xhi + (size_t)NT * DD;         // NT*DD bf16
    __hip_bfloat16* BT  = xlo + (size_t)NT * DD;         // 1152*768 bf16
    float* bcat = (float*)(BT + (size_t)NCOLS * KBIG);   // 1152 f32

    k0_prep<<<K0A_BLKS + K0B_BLKS + K0C_BLKS + K0D_BLKS, 256, 0, stream>>>(
        x, ke_w1, ke_b1, qe_w1, qe_b1, lke_w1, lke_b1, gate_w1, gate_b1, v_w, v_b,
        ke_w2, qe_w2, lke_w2, gate_w2, out_w, xhi, xlo, BT, bcat, W2T, OWT);
    k1_mfma<<<dim3(NT / 128, NCOLS / 64), 256, 0, stream>>>(xhi, xlo, BT, bcat,
                                                            Hhi, Hlo, V);
    k2_fused<<<NT / 16, 256, 0, stream>>>(Hhi, Hlo, W2T,
                                          ke_b2, qe_b2, lke_b2, gate_b2,
                                          set_weights, pos_weight,
                                          ltm_weight, ltm_count, pos_freqs,
                                          Fk, Fq, Fql, J);
    k3a_scan<<<BB, 512, 0, stream>>>(J, wg, resonance_scale, resonance_threshold,
                                     surprise_scale, surprise_bias);
    k4a_state<<<dim3(NC, 4), 256, 0, stream>>>(Fk, wg, V, S);
    k4b_scan<<<dim3(SST / 256, BB), 256, 0, stream>>>(S, M);
    k4c_ln<<<dim3(NC, 8), 256, 0, stream>>>(Fq, Fk, wg, Fql, V, M, ltm_mem,
                                            out_ln_g, out_ln_b, Hnhi, Hnlo);
    k5b_mfma<<<dim3(NT / 64, DD / 64), 256, 0, stream>>>(Hnhi, Hnlo, OWT, out_b,
                                                         (float*)d_out);
}